// Round 1
// baseline (11838.004 us; speedup 1.0000x reference)
//
#include <hip/hip_runtime.h>
#include <stdint.h>

typedef short  s8v  __attribute__((ext_vector_type(8)));
typedef float  f4v  __attribute__((ext_vector_type(4)));
typedef int    i4v  __attribute__((ext_vector_type(4)));

#define MFMA16(a,b,c) __builtin_amdgcn_mfma_f32_16x16x32_bf16(a,b,c,0,0,0)

#define K1 1.44269504088896340f   /* log2(e)   */
#define K2 2.88539008177792681f   /* 2*log2(e) */

__device__ __forceinline__ unsigned short f2bf(float f) {
  union { float f; uint32_t u; } v; v.f = f;
  return (unsigned short)((v.u + 0x7FFFu + ((v.u >> 16) & 1u)) >> 16);
}
__device__ __forceinline__ float bflo(uint32_t dw) {
  union { uint32_t u; float f; } v; v.u = dw << 16; return v.f;
}
__device__ __forceinline__ float bfhi(uint32_t dw) {
  union { uint32_t u; float f; } v; v.u = dw & 0xFFFF0000u; return v.f;
}

// ---------------- prep: convert weights to bf16, sum biases ----------------
__global__ __launch_bounds__(256) void prep_kernel(
    const float* __restrict__ We, const float* __restrict__ Ue,
    const float* __restrict__ Wih, const float* __restrict__ Whh,
    const float* __restrict__ bih, const float* __restrict__ bhh,
    unsigned short* __restrict__ Wih_b, unsigned short* __restrict__ Whh_b,
    unsigned short* __restrict__ We_b, unsigned short* __restrict__ Ue_b,
    float* __restrict__ bsum)
{
  int i0 = blockIdx.x * 256 + threadIdx.x;
  int stride = gridDim.x * 256;
  for (int i = i0; i < 262144; i += stride) Wih_b[i] = f2bf(Wih[i]);
  for (int i = i0; i < 262144; i += stride) Whh_b[i] = f2bf(Whh[i]);
  for (int i = i0; i < 65536;  i += stride) We_b[i]  = f2bf(We[i]);
  for (int i = i0; i < 16384;  i += stride) Ue_b[i]  = f2bf(Ue[i]);
  for (int i = i0; i < 1024;   i += stride) bsum[i]  = bih[i] + bhh[i];
}

// ---------------- Ux GEMM: UxK[b][n][s] = K2 * sum_t x[b][t][n]*U_e[s][t] ---
// grid: 2048*4 blocks (b, n-chunk of 64), 256 threads (4 waves)
__global__ __launch_bounds__(256) void ux_kernel(
    const float* __restrict__ x, const unsigned short* __restrict__ Ue_b,
    unsigned short* __restrict__ UxK)
{
  __shared__ unsigned short xT[64 * 136];  // x[b][t'][n] transposed -> [n][t'], padded
  __shared__ unsigned short oT[64 * 136];
  const int tid = threadIdx.x;
  const int b   = blockIdx.x >> 2;
  const int n0  = (blockIdx.x & 3) * 64;

  {
    const int nl = tid & 63, tp = tid >> 6;
    for (int i = 0; i < 32; i++) {
      int t = tp + i * 4;
      xT[nl * 136 + t] = f2bf(x[((size_t)b * 128 + t) * 256 + n0 + nl]);
    }
  }
  __syncthreads();
  {
    const int w = tid >> 6, lane = tid & 63;
    const int l15 = lane & 15, quad = lane >> 4;
    for (int tt = 0; tt < 8; tt++) {
      f4v acc = {0.f, 0.f, 0.f, 0.f};
      #pragma unroll
      for (int kt = 0; kt < 4; kt++) {
        s8v a  = *(const s8v*)&xT[(w * 16 + l15) * 136 + kt * 32 + quad * 8];
        s8v bb = *(const s8v*)&Ue_b[(tt * 16 + l15) * 128 + kt * 32 + quad * 8];
        acc = MFMA16(a, bb, acc);
      }
      #pragma unroll
      for (int r = 0; r < 4; r++)
        oT[(w * 16 + quad * 4 + r) * 136 + tt * 16 + l15] = f2bf(acc[r] * K2);
    }
  }
  __syncthreads();
  {
    for (int p = 0; p < 2; p++) {
      int row = (tid >> 3) + p * 32;
      int c16 = (tid & 7) * 16;
      const i4v* src = (const i4v*)&oT[row * 136 + c16];
      i4v* dst = (i4v*)&UxK[(((size_t)b * 256) + n0 + row) * 128 + c16];
      dst[0] = src[0];
      dst[1] = src[1];
    }
  }
}

// ---------------- persistent recurrence: 256 blocks x 1024 thr, 8 batch/blk --
__global__ __launch_bounds__(1024, 4) void rnn_kernel(
    const unsigned short* __restrict__ UxK,
    const unsigned short* __restrict__ We_b,
    const unsigned short* __restrict__ Wih_b,
    const unsigned short* __restrict__ Whh_b,
    const float* __restrict__ bsum_g,
    const float* __restrict__ Ve,
    float* __restrict__ out)
{
  __shared__ float  h_hist[8 * 256 * 8];        // 64 KB: h history, 8 steps
  __shared__ unsigned short xt_b[16 * 264];     // bf16, rows 8..15 zero-pad
  __shared__ unsigned short h_b [16 * 264];
  __shared__ unsigned short c_b [16 * 264];
  __shared__ float  c_f[8 * 256];               // f32 cell state
  __shared__ float  e_f[8 * 256];
  __shared__ float  wv_lds[8 * 128 * 2];        // [b][t] -> (K2*whs, -2*V)
  __shared__ float  bsum[1024];
  __shared__ float  Zp[16];
  __shared__ float  Zi[8];

  const int tid  = threadIdx.x;
  const int wv   = tid >> 6;
  const int lane = tid & 63;
  const int l15  = lane & 15;
  const int quad = lane >> 4;

  for (int i = tid; i < 16 * 264; i += 1024) { xt_b[i] = 0; h_b[i] = 0; c_b[i] = 0; }
  for (int i = tid; i < 2048; i += 1024) c_f[i] = 0.f;
  bsum[tid] = bsum_g[tid];
  {
    int b8 = tid >> 7, t = tid & 127;
    wv_lds[(b8 * 128 + t) * 2 + 1] = -2.0f * Ve[t];
    wv_lds[(b8 * 128 + t) * 2 + 0] = 0.f;
  }
  float Vs = 0.f;
  for (int t = 0; t < 128; t++) Vs += Ve[t];
  __syncthreads();

  const int an = tid & 255;   // n index owned by this thread
  const int bq = tid >> 8;    // handles batches bq and bq+4

  f4v ga0, ga1, ga2, ga3;

  for (int s = 0; s < 128; s++) {
    __syncthreads();   // B1: h_b/c_b stable from previous step

    // ---- whs = [h,c] @ W_e.T  (waves 0..7, t-tile = wv) ----
    if (wv < 8) {
      f4v acc = {0.f, 0.f, 0.f, 0.f};
      #pragma unroll
      for (int kt = 0; kt < 8; kt++) {
        s8v a  = *(const s8v*)&h_b[l15 * 264 + kt * 32 + quad * 8];
        s8v bb = *(const s8v*)&We_b[(wv * 16 + l15) * 512 + kt * 32 + quad * 8];
        acc = MFMA16(a, bb, acc);
      }
      #pragma unroll
      for (int kt = 0; kt < 8; kt++) {
        s8v a  = *(const s8v*)&c_b[l15 * 264 + kt * 32 + quad * 8];
        s8v bb = *(const s8v*)&We_b[(wv * 16 + l15) * 512 + 256 + kt * 32 + quad * 8];
        acc = MFMA16(a, bb, acc);
      }
      if (lane < 32) {
        #pragma unroll
        for (int r = 0; r < 4; r++)
          wv_lds[((quad * 4 + r) * 128 + wv * 16 + l15) * 2] = K2 * acc[r];
      }
    }
    __syncthreads();   // B2: whsK ready

    // ---- h-part of gates (all 16 waves) — overlaps with attention below ----
    ga0 = (f4v){0.f,0.f,0.f,0.f}; ga1 = ga0; ga2 = ga0; ga3 = ga0;
    #pragma unroll
    for (int kt = 0; kt < 8; kt++) {
      s8v a = *(const s8v*)&h_b[l15 * 264 + kt * 32 + quad * 8];
      int ko = kt * 32 + quad * 8;
      s8v b0 = *(const s8v*)&Whh_b[(size_t)(  0 + wv * 16 + l15) * 256 + ko];
      s8v b1 = *(const s8v*)&Whh_b[(size_t)(256 + wv * 16 + l15) * 256 + ko];
      s8v b2 = *(const s8v*)&Whh_b[(size_t)(512 + wv * 16 + l15) * 256 + ko];
      s8v b3 = *(const s8v*)&Whh_b[(size_t)(768 + wv * 16 + l15) * 256 + ko];
      ga0 = MFMA16(a, b0, ga0);
      ga1 = MFMA16(a, b1, ga1);
      ga2 = MFMA16(a, b2, ga2);
      ga3 = MFMA16(a, b3, ga3);
    }

    // ---- attention: e[b][n] = Vs + sum_t (-2 V[t]) / (exp2(UxK+whsK)+1) ----
    #pragma unroll
    for (int pass = 0; pass < 2; pass++) {
      const int bb8 = bq + pass * 4;
      const i4v* up4 = (const i4v*)(UxK + (((size_t)blockIdx.x * 8 + bb8) * 256 + an) * 128);
      const float* wvp = &wv_lds[bb8 * 256];
      float acc0 = 0.f, acc1 = 0.f;
      #pragma unroll 4
      for (int tg = 0; tg < 16; tg++) {
        i4v d = up4[tg];
        #pragma unroll
        for (int q = 0; q < 4; q++) {
          uint32_t dw = (uint32_t)d[q];
          int t2 = (tg * 8 + q * 2) * 2;
          float2 p0 = *(const float2*)&wvp[t2];
          float2 p1 = *(const float2*)&wvp[t2 + 2];
          float x0 = bflo(dw) + p0.x;
          float r0 = __builtin_amdgcn_rcpf(__builtin_amdgcn_exp2f(x0) + 1.0f);
          acc0 = fmaf(p0.y, r0, acc0);
          float x1 = bfhi(dw) + p1.x;
          float r1 = __builtin_amdgcn_rcpf(__builtin_amdgcn_exp2f(x1) + 1.0f);
          acc1 = fmaf(p1.y, r1, acc1);
        }
      }
      e_f[bb8 * 256 + an] = Vs + acc0 + acc1;
    }
    __syncthreads();  // B3: e ready

    // ---- softmax over n (no max-sub: |e| <= sum|V| ~ 5, f32-safe) ----
    const int b8s = tid >> 7;
    const int nn0 = (tid & 127) * 2;
    float e0 = e_f[b8s * 256 + nn0];
    float e1 = e_f[b8s * 256 + nn0 + 1];
    float p0 = __builtin_amdgcn_exp2f(K1 * e0);
    float p1 = __builtin_amdgcn_exp2f(K1 * e1);
    float ssum = p0 + p1;
    #pragma unroll
    for (int off = 32; off >= 1; off >>= 1) ssum += __shfl_xor(ssum, off);
    if (lane == 0) Zp[wv] = ssum;
    __syncthreads();
    if (tid < 8) Zi[tid] = 1.0f / (Zp[2 * tid] + Zp[2 * tid + 1]);
    __syncthreads();
    {
      float zi = Zi[b8s];
      unsigned int packed = (unsigned int)f2bf(p0 * zi * e0)
                          | ((unsigned int)f2bf(p1 * zi * e1) << 16);
      *(unsigned int*)&xt_b[b8s * 264 + nn0] = packed;
    }
    __syncthreads();  // B5: xt ready

    // ---- xt-part of gates ----
    #pragma unroll
    for (int kt = 0; kt < 8; kt++) {
      s8v a = *(const s8v*)&xt_b[l15 * 264 + kt * 32 + quad * 8];
      int ko = kt * 32 + quad * 8;
      s8v b0 = *(const s8v*)&Wih_b[(size_t)(  0 + wv * 16 + l15) * 256 + ko];
      s8v b1 = *(const s8v*)&Wih_b[(size_t)(256 + wv * 16 + l15) * 256 + ko];
      s8v b2 = *(const s8v*)&Wih_b[(size_t)(512 + wv * 16 + l15) * 256 + ko];
      s8v b3 = *(const s8v*)&Wih_b[(size_t)(768 + wv * 16 + l15) * 256 + ko];
      ga0 = MFMA16(a, b0, ga0);
      ga1 = MFMA16(a, b1, ga1);
      ga2 = MFMA16(a, b2, ga2);
      ga3 = MFMA16(a, b3, ga3);
    }

    // ---- pointwise LSTM straight from accumulators (lanes 0..31) ----
    if (lane < 32) {
      const int jj = wv * 16 + l15;
      #pragma unroll
      for (int r = 0; r < 4; r++) {
        const int m = quad * 4 + r;
        float iG = ga0[r] + bsum[jj];
        float fG = ga1[r] + bsum[256 + jj];
        float gG = ga2[r] + bsum[512 + jj];
        float oG = ga3[r] + bsum[768 + jj];
        float si = __builtin_amdgcn_rcpf(1.0f + __builtin_amdgcn_exp2f(-K1 * iG));
        float sf = __builtin_amdgcn_rcpf(1.0f + __builtin_amdgcn_exp2f(-K1 * fG));
        float so = __builtin_amdgcn_rcpf(1.0f + __builtin_amdgcn_exp2f(-K1 * oG));
        float tg_ = 1.0f - 2.0f * __builtin_amdgcn_rcpf(1.0f + __builtin_amdgcn_exp2f(K2 * gG));
        float cn = sf * c_f[m * 256 + jj] + si * tg_;
        float th = 1.0f - 2.0f * __builtin_amdgcn_rcpf(1.0f + __builtin_amdgcn_exp2f(K2 * cn));
        float hn = so * th;
        c_f[m * 256 + jj] = cn;
        c_b[m * 264 + jj] = f2bf(cn);
        h_b[m * 264 + jj] = f2bf(hn);
        h_hist[(m * 256 + jj) * 8 + (s & 7)] = hn;
      }
    }

    // ---- coalesced output dump every 8 steps ----
    if ((s & 7) == 7) {
      __syncthreads();
      #pragma unroll
      for (int p = 0; p < 2; p++) {
        int rid = p * 1024 + tid;
        int mB = rid >> 8, j = rid & 255;
        const f4v* src = (const f4v*)&h_hist[rid * 8];
        f4v* dst = (f4v*)&out[(((size_t)blockIdx.x * 8 + mB) * 256 + j) * 128 + (s - 7)];
        __builtin_nontemporal_store(src[0], dst);
        __builtin_nontemporal_store(src[1], dst + 1);
      }
    }
  }
}

extern "C" void kernel_launch(void* const* d_in, const int* in_sizes, int n_in,
                              void* d_out, int out_size, void* d_ws, size_t ws_size,
                              hipStream_t stream) {
  const float* x   = (const float*)d_in[0];
  const float* We  = (const float*)d_in[1];
  const float* Ue  = (const float*)d_in[2];
  const float* Ve  = (const float*)d_in[3];
  const float* Wih = (const float*)d_in[4];
  const float* Whh = (const float*)d_in[5];
  const float* bih = (const float*)d_in[6];
  const float* bhh = (const float*)d_in[7];
  float* out = (float*)d_out;

  char* p = (char*)d_ws;
  unsigned short* UxK   = (unsigned short*)p; p += (size_t)134217728; // 2048*256*128 bf16
  unsigned short* Wih_b = (unsigned short*)p; p += 524288;
  unsigned short* Whh_b = (unsigned short*)p; p += 524288;
  unsigned short* We_b  = (unsigned short*)p; p += 131072;
  unsigned short* Ue_b  = (unsigned short*)p; p += 32768;
  float* bsum = (float*)p;

  prep_kernel<<<512, 256, 0, stream>>>(We, Ue, Wih, Whh, bih, bhh,
                                       Wih_b, Whh_b, We_b, Ue_b, bsum);
  ux_kernel<<<8192, 256, 0, stream>>>(x, Ue_b, UxK);
  rnn_kernel<<<256, 1024, 0, stream>>>(UxK, We_b, Wih_b, Whh_b, bsum, Ve, out);
}